// Round 10
// baseline (1113.595 us; speedup 1.0000x reference)
//
#include <hip/hip_runtime.h>
#include <hip/hip_bf16.h>

#define NPTS 692736      // 24*41*16*44
#define NPATCH 16896     // 24*16*44

// ---------- module-scope device globals: zero d_ws dependency ----------
__device__ float  v10_xbuf[NPATCH*256];
__device__ float  v10_ctx[NPATCH*64];
__device__ float  v10_depth[NPATCH*41];
__device__ int    v10_ranks[NPTS];
__device__ float  v10_bev[16384*64];
__device__ float  v10_w2[64*64*9];
__device__ double v10_geom[24*24];

__device__ __forceinline__ void inv3_v10(const double* m, double* o){
  double a=m[0],b=m[1],c=m[2],d=m[3],e=m[4],f=m[5],g=m[6],h=m[7],i=m[8];
  double A = e*i - f*h, B = -(d*i - f*g), C = d*h - e*g;
  double det = a*A + b*B + c*C;
  double id = 1.0/det;
  o[0]=A*id;            o[1]=-(b*i - c*h)*id; o[2]=(b*f - c*e)*id;
  o[3]=B*id;            o[4]=(a*i - c*g)*id;  o[5]=-(a*f - c*d)*id;
  o[6]=C*id;            o[7]=-(a*h - b*g)*id; o[8]=(a*e - b*d)*id;
}

__global__ void zero_v10(){
  v10_bev[blockIdx.x*256 + threadIdx.x] = 0.f;
}

__global__ void geom_v10(const float* rots, const float* trans, const float* intrins,
                         const float* post_rots, const float* post_trans){
  int t = threadIdx.x;
  if (t >= 24) return;
  double pr[9], it[9], r[9];
  for (int i=0;i<9;i++){
    pr[i] = (double)post_rots[t*9+i];
    it[i] = (double)intrins[t*9+i];
    r[i]  = (double)rots[t*9+i];
  }
  double ipr[9], iit[9];
  inv3_v10(pr, ipr); inv3_v10(it, iit);
  double* g = v10_geom + t*24;
  for (int i=0;i<3;i++) for(int j=0;j<3;j++){
    double s=0; for(int k=0;k<3;k++) s += r[i*3+k]*iit[k*3+j];
    g[9+i*3+j]=s;
  }
  for (int i=0;i<9;i++) g[i]   = ipr[i];
  for (int i=0;i<3;i++) g[18+i]= (double)post_trans[t*3+i];
  for (int i=0;i<3;i++) g[21+i]= (double)trans[t*3+i];
}

// conv1 16x16 stride-16 VALID as patch-GEMM + BN1 + ReLU
__global__ __launch_bounds__(256) void conv1_v10(const float* img, const float* cw,
    const float* cb, const float* g1, const float* b1, const float* m1, const float* v1){
  __shared__ float patch[8*768];   // 24,576 B
  __shared__ float wl[256*17];     // 17,408 B
  int tid = threadIdx.x;
  int pbase = blockIdx.x * 8;
  for (int l = tid; l < 8*768; l += 256){
    int pp = l / 768, k = l % 768;
    int p = pbase + pp;
    int im = p / 704, pix = p % 704;
    int ph = pix / 44, pw = pix % 44;
    int c = k >> 8, rem = k & 255, ky = rem >> 4, kx = rem & 15;
    patch[pp*768+k] = img[(size_t)im*540672 + (size_t)c*180224 +
                          (size_t)(ph*16+ky)*704 + (pw*16+kx)];
  }
  float acc[8];
  #pragma unroll
  for (int pp=0;pp<8;pp++) acc[pp]=0.f;
  for (int kt=0; kt<768; kt+=16){
    __syncthreads();
    for (int l = tid; l < 256*16; l += 256){
      int o = l >> 4, kk = l & 15;
      wl[o*17+kk] = cw[o*768 + kt + kk];
    }
    __syncthreads();
    for (int kk=0; kk<16; kk++){
      float wv = wl[tid*17+kk];
      int k = kt+kk;
      #pragma unroll
      for (int pp=0;pp<8;pp++) acc[pp] += patch[pp*768+k]*wv;
    }
  }
  float scale = g1[tid] / sqrtf(v1[tid] + 1e-5f);
  float shift = b1[tid] - m1[tid]*scale;
  float bias  = cb[tid];
  for (int pp=0;pp<8;pp++){
    float v = (acc[pp]+bias)*scale + shift;
    v10_xbuf[(size_t)(pbase+pp)*256 + tid] = v > 0.f ? v : 0.f;
  }
}

// depth head (105x256) + softmax over 41 + ctx split
__global__ __launch_bounds__(128) void depth_v10(const float* dw, const float* db){
  __shared__ float xv[256];
  __shared__ float yv[105];
  __shared__ float ev[41];
  __shared__ float red[2];
  int p = blockIdx.x;
  int t = threadIdx.x;
  xv[t]      = v10_xbuf[(size_t)p*256 + t];
  xv[t+128]  = v10_xbuf[(size_t)p*256 + t + 128];
  __syncthreads();
  if (t < 105){
    float s = db[t];
    const float* wr = dw + t*256;
    for (int c=0;c<256;c++) s += wr[c]*xv[c];
    yv[t] = s;
  }
  __syncthreads();
  if (t >= 64 && t < 128) v10_ctx[(size_t)p*64 + (t-64)] = yv[41 + (t-64)];
  if (t == 0){
    float m = yv[0];
    for (int i=1;i<41;i++) m = fmaxf(m, yv[i]);
    red[0] = m;
  }
  __syncthreads();
  if (t < 41) ev[t] = expf(yv[t] - red[0]);
  __syncthreads();
  if (t == 0){
    float s = 0.f;
    for (int i=0;i<41;i++) s += ev[i];
    red[1] = s;
  }
  __syncthreads();
  if (t < 41) v10_depth[(size_t)p*41 + t] = ev[t]/red[1];
}

// voxel rank per frustum point (trunc-toward-zero, rank aliasing allowed)
__global__ __launch_bounds__(256) void rank_v10(){
  int idx = blockIdx.x*256 + threadIdx.x;
  if (idx >= NPTS) return;
  int im = idx / 28864;
  int r  = idx % 28864;
  int d  = r / 704; int pix = r % 704;
  int h = pix / 44, w = pix % 44;
  const double* g = v10_geom + im*24;
  double fx = (double)w * (703.0/43.0);
  double fy = (double)h * 17.0;
  double fz = 4.0 + (double)d;
  double px = fx - g[18], py = fy - g[19], pz = fz - g[20];
  double q0 = g[0]*px + g[1]*py + g[2]*pz;
  double q1 = g[3]*px + g[4]*py + g[5]*pz;
  double q2 = g[6]*px + g[7]*py + g[8]*pz;
  q0 *= q2; q1 *= q2;
  double o0 = g[9]*q0  + g[10]*q1 + g[11]*q2 + g[21];
  double o1 = g[12]*q0 + g[13]*q1 + g[14]*q2 + g[22];
  double o2 = g[15]*q0 + g[16]*q1 + g[17]*q2 + g[23];
  int cx = (int)((o0 + 51.2)/0.8);
  int cy = (int)((o1 + 51.2)/0.8);
  int cz = (int)((o2 + 10.0)/20.0);
  int rank = cx + cy*128 + cz*16384;
  v10_ranks[idx] = (rank >= 0 && rank < 16384) ? rank : -1;
}

// scatter: one lane per (point, channel)
__global__ __launch_bounds__(256) void scatter_v10(){
  long long gid = (long long)blockIdx.x*256 + threadIdx.x;
  int idx = (int)(gid >> 6);
  int c   = (int)(gid & 63);
  if (idx >= NPTS) return;
  int rank = v10_ranks[idx];
  if (rank < 0) return;
  int im = idx / 28864;
  int r  = idx % 28864;
  int d  = r / 704; int pix = r % 704;
  int p = im*704 + pix;
  float val = v10_ctx[(size_t)p*64 + c] * v10_depth[(size_t)p*41 + d];
  atomicAdd(v10_bev + (size_t)rank*64 + c, val);
}

// bev output: [yx][c] -> out1[c][y][x] fp32
__global__ void bevout_v10(float* out1){
  int gid = blockIdx.x*256 + threadIdx.x;
  int c  = gid >> 14;
  int yx = gid & 16383;
  out1[gid] = v10_bev[(size_t)yx*64 + c];
}

// fold enc_w concat([bev,bev]) halves
__global__ void w2_v10(const float* enc_w){
  int gid = blockIdx.x*256 + threadIdx.x;
  if (gid >= 36864) return;
  int o = gid / 576; int rem = gid % 576;
  int ic = rem / 9, t = rem % 9;
  v10_w2[gid] = enc_w[o*1152 + ic*9 + t] + enc_w[o*1152 + (ic+64)*9 + t];
}

// conv2 3x3 SAME + BN2 + ReLU + 7x64 head, fused (LDS 51.2 KB)
__global__ __launch_bounds__(256) void conv2_v10(
    const float* eb, const float* g2, const float* b2_, const float* m2, const float* v2,
    const float* hw, const float* hb, float* out0){
  __shared__ float itile[64*100];     // 25,600 B
  __shared__ float wtile[64*72];      // 18,432 B
  __shared__ float hred[4*64*7];      //  7,168 B
  int tid = threadIdx.x;
  int og  = tid >> 6;
  int pix = tid & 63;
  int py = pix >> 3, px = pix & 7;
  int by = blockIdx.y, bx = blockIdx.x;
  for (int l = tid; l < 6400; l += 256){
    int ic = l / 100, rem = l % 100;
    int iy = rem / 10, ix = rem % 10;
    int gy = by*8 + iy - 1, gx = bx*8 + ix - 1;
    itile[l] = (gy>=0 && gy<128 && gx>=0 && gx<128) ? v10_bev[(size_t)(gy*128+gx)*64 + ic] : 0.f;
  }
  float acc[16];
  #pragma unroll
  for (int j=0;j<16;j++) acc[j]=0.f;
  for (int it=0; it<64; it+=8){
    __syncthreads();
    for (int l = tid; l < 64*72; l += 256){
      int oc = l / 72, rem = l % 72;
      wtile[l] = v10_w2[oc*576 + it*9 + rem];
    }
    __syncthreads();
    for (int icl=0; icl<8; icl++){
      int ic = it + icl;
      const float* ibase = itile + ic*100 + py*10 + px;
      float iv[9];
      #pragma unroll
      for (int t=0;t<9;t++) iv[t] = ibase[(t/3)*10 + (t%3)];
      const float* wbase = wtile + (og*16)*72 + icl*9;
      #pragma unroll
      for (int j=0;j<16;j++){
        #pragma unroll
        for (int t=0;t<9;t++) acc[j] += iv[t]*wbase[j*72+t];
      }
    }
  }
  float part[7];
  #pragma unroll
  for (int o=0;o<7;o++) part[o]=0.f;
  for (int j=0;j<16;j++){
    int oc = og*16+j;
    float scale = g2[oc]/sqrtf(v2[oc]+1e-5f);
    float shift = b2_[oc] - m2[oc]*scale;
    float v = (acc[j] + eb[oc])*scale + shift;
    v = v > 0.f ? v : 0.f;
    #pragma unroll
    for (int o=0;o<7;o++) part[o] += hw[o*64+oc]*v;
  }
  __syncthreads();
  for (int o=0;o<7;o++) hred[(og*64+pix)*7+o] = part[o];
  __syncthreads();
  if (og == 0){
    int gy = by*8+py, gx = bx*8+px;
    for (int o=0;o<7;o++){
      float s = hred[pix*7+o] + hred[(64+pix)*7+o] + hred[(128+pix)*7+o]
              + hred[(192+pix)*7+o] + hb[o];
      out0[o*16384 + gy*128 + gx] = s;
    }
  }
}

extern "C" void kernel_launch(void* const* d_in, const int* in_sizes, int n_in,
                              void* d_out, int out_size, void* d_ws, size_t ws_size,
                              hipStream_t stream){
  const float* imgs       = (const float*)d_in[0];
  const float* rots       = (const float*)d_in[1];
  const float* trans      = (const float*)d_in[2];
  const float* intrins    = (const float*)d_in[3];
  const float* post_rots  = (const float*)d_in[4];
  const float* post_trans = (const float*)d_in[5];
  const float* conv_w     = (const float*)d_in[6];
  const float* conv_b     = (const float*)d_in[7];
  const float* bn1_g      = (const float*)d_in[8];
  const float* bn1_b      = (const float*)d_in[9];
  const float* bn1_m      = (const float*)d_in[10];
  const float* bn1_v      = (const float*)d_in[11];
  const float* depth_w    = (const float*)d_in[12];
  const float* depth_b    = (const float*)d_in[13];
  const float* enc_w      = (const float*)d_in[14];
  const float* enc_b      = (const float*)d_in[15];
  const float* bn2_g      = (const float*)d_in[16];
  const float* bn2_b      = (const float*)d_in[17];
  const float* bn2_m      = (const float*)d_in[18];
  const float* bn2_v      = (const float*)d_in[19];
  const float* head_w     = (const float*)d_in[20];
  const float* head_b     = (const float*)d_in[21];

  // fp32 outputs: reference returns float32 arrays
  float* out0 = (float*)d_out;          // (1,7,128,128)  = 114688 floats
  float* out1 = out0 + 114688;          // (1,64,128,128) = 1048576 floats

  zero_v10<<<4096, 256, 0, stream>>>();
  geom_v10<<<1, 32, 0, stream>>>(rots, trans, intrins, post_rots, post_trans);
  conv1_v10<<<NPATCH/8, 256, 0, stream>>>(imgs, conv_w, conv_b, bn1_g, bn1_b, bn1_m, bn1_v);
  depth_v10<<<NPATCH, 128, 0, stream>>>(depth_w, depth_b);
  rank_v10<<<NPTS/256, 256, 0, stream>>>();
  scatter_v10<<<(NPTS*64)/256, 256, 0, stream>>>();
  w2_v10<<<144, 256, 0, stream>>>(enc_w);
  bevout_v10<<<4096, 256, 0, stream>>>(out1);
  conv2_v10<<<dim3(16,16), 256, 0, stream>>>(enc_b, bn2_g, bn2_b, bn2_m, bn2_v,
                                             head_w, head_b, out0);
}

// Round 11
// 809.341 us; speedup vs baseline: 1.3759x; 1.3759x over previous
//
#include <hip/hip_runtime.h>
#include <hip/hip_bf16.h>

#define NPTS 692736      // 24*41*16*44
#define NPATCH 16896     // 24*16*44

// ---------- module-scope device globals ----------
__device__ float  v11_xbuf[NPATCH*256];
__device__ float  v11_ctx[NPATCH*64];
__device__ float  v11_depth[NPATCH*41];
__device__ int    v11_ranks[NPTS];
__device__ float  v11_bev[16384*64];
__device__ float  v11_w2[64*64*9];
__device__ float  v11_wT[768*256];     // conv_w transposed to [k][o]
__device__ double v11_geom[24*24];

__device__ __forceinline__ void inv3_v11(const double* m, double* o){
  double a=m[0],b=m[1],c=m[2],d=m[3],e=m[4],f=m[5],g=m[6],h=m[7],i=m[8];
  double A = e*i - f*h, B = -(d*i - f*g), C = d*h - e*g;
  double det = a*A + b*B + c*C;
  double id = 1.0/det;
  o[0]=A*id;            o[1]=-(b*i - c*h)*id; o[2]=(b*f - c*e)*id;
  o[3]=B*id;            o[4]=(a*i - c*g)*id;  o[5]=-(a*f - c*d)*id;
  o[6]=C*id;            o[7]=-(a*h - b*g)*id; o[8]=(a*e - b*d)*id;
}

__global__ void zero_v11(){
  v11_bev[blockIdx.x*256 + threadIdx.x] = 0.f;
}

__global__ void geom_v11(const float* rots, const float* trans, const float* intrins,
                         const float* post_rots, const float* post_trans){
  int t = threadIdx.x;
  if (t >= 24) return;
  double pr[9], it[9], r[9];
  for (int i=0;i<9;i++){
    pr[i] = (double)post_rots[t*9+i];
    it[i] = (double)intrins[t*9+i];
    r[i]  = (double)rots[t*9+i];
  }
  double ipr[9], iit[9];
  inv3_v11(pr, ipr); inv3_v11(it, iit);
  double* g = v11_geom + t*24;
  for (int i=0;i<3;i++) for(int j=0;j<3;j++){
    double s=0; for(int k=0;k<3;k++) s += r[i*3+k]*iit[k*3+j];
    g[9+i*3+j]=s;
  }
  for (int i=0;i<9;i++) g[i]   = ipr[i];
  for (int i=0;i<3;i++) g[18+i]= (double)post_trans[t*3+i];
  for (int i=0;i<3;i++) g[21+i]= (double)trans[t*3+i];
}

// transpose conv_w [256 o][768 k] -> wT [768 k][256 o]
__global__ void wt_v11(const float* cw){
  int gid = blockIdx.x*256 + threadIdx.x;   // 196608
  int k = gid >> 8, o = gid & 255;
  v11_wT[gid] = cw[o*768 + k];
}

// conv1 as register-blocked GEMM: block = 32 patches x 256 ch, thread = 8pp x 4ch
__global__ __launch_bounds__(256) void conv1_v11(const float* img,
    const float* cb, const float* g1, const float* b1, const float* m1, const float* v1){
  __shared__ float sp[32*36];    // [kk][pp], stride 36 (16B-aligned, bank-spread)
  __shared__ float sw[32*256];   // [kk][ch]
  int tid = threadIdx.x;
  int cg = tid & 63;             // 64 ch-groups x 4ch
  int pg = tid >> 6;             // 4 patch-groups x 8pp
  int pbase = blockIdx.x*32;
  int im = pbase/704;            // 704 % 32 == 0: all patches same image

  float acc[4][8];
  #pragma unroll
  for (int j=0;j<4;j++)
    #pragma unroll
    for (int i=0;i<8;i++) acc[j][i]=0.f;

  for (int kt=0; kt<768; kt+=32){
    __syncthreads();
    // stage weights (coalesced from transposed wT)
    for (int l = tid; l < 8192; l += 256)
      sw[l] = v11_wT[(kt + (l>>8))*256 + (l&255)];
    // stage patches
    for (int l = tid; l < 1024; l += 256){
      int kk = l>>5, pp = l&31;
      int k = kt + kk;
      int p = pbase + pp;
      int pix = p % 704;
      int ph = pix/44, pw = pix%44;
      int c = k>>8, rem = k&255, ky = rem>>4, kx = rem&15;
      sp[kk*36+pp] = img[(size_t)im*540672 + (size_t)c*180224 +
                         (size_t)(ph*16+ky)*704 + (pw*16+kx)];
    }
    __syncthreads();
    #pragma unroll 8
    for (int kk=0; kk<32; kk++){
      float4 p0 = *(const float4*)&sp[kk*36 + pg*8];
      float4 p1 = *(const float4*)&sp[kk*36 + pg*8 + 4];
      float4 wv = *(const float4*)&sw[kk*256 + cg*4];
      float pv[8] = {p0.x,p0.y,p0.z,p0.w,p1.x,p1.y,p1.z,p1.w};
      float wa[4] = {wv.x,wv.y,wv.z,wv.w};
      #pragma unroll
      for (int j=0;j<4;j++)
        #pragma unroll
        for (int i=0;i<8;i++) acc[j][i] += wa[j]*pv[i];
    }
  }
  // BN + ReLU epilogue, coalesced float4 stores
  float sc[4], sh[4], bi[4];
  #pragma unroll
  for (int j=0;j<4;j++){
    int ch = cg*4+j;
    sc[j] = g1[ch] / sqrtf(v1[ch] + 1e-5f);
    sh[j] = b1[ch] - m1[ch]*sc[j];
    bi[j] = cb[ch];
  }
  #pragma unroll
  for (int i=0;i<8;i++){
    int p = pbase + pg*8 + i;
    float4 v;
    float t0 = (acc[0][i]+bi[0])*sc[0] + sh[0]; v.x = t0>0.f?t0:0.f;
    float t1 = (acc[1][i]+bi[1])*sc[1] + sh[1]; v.y = t1>0.f?t1:0.f;
    float t2 = (acc[2][i]+bi[2])*sc[2] + sh[2]; v.z = t2>0.f?t2:0.f;
    float t3 = (acc[3][i]+bi[3])*sc[3] + sh[3]; v.w = t3>0.f?t3:0.f;
    *(float4*)&v11_xbuf[(size_t)p*256 + cg*4] = v;
  }
}

// depth head as blocked GEMM + softmax + ctx split: block = 32 patches
__global__ __launch_bounds__(256) void depth_v11(const float* dw, const float* db){
  __shared__ float sx[32*260];    // [pp][c], stride 260 (33,280 B)
  __shared__ float sdw[105*36];   // [o][c-chunk 32], stride 36 (15,120 B)
  __shared__ float sy[32*112];    // [pp][o] accum (14,336 B)
  int tid = threadIdx.x;
  int pbase = blockIdx.x*32;
  // load x tile
  for (int l = tid; l < 8192; l += 256){
    int pp = l>>8, c = l&255;
    sx[pp*260+c] = v11_xbuf[(size_t)(pbase+pp)*256 + c];
  }
  // init y with bias
  for (int l = tid; l < 32*105; l += 256){
    int pp = l/105, o = l%105;
    sy[pp*112+o] = db[o];
  }
  int ppg = tid >> 4;   // 16 groups x 2 pp
  int og  = tid & 15;   // 16 groups x 7 o
  for (int ch = 0; ch < 8; ch++){       // 8 chunks of 32 c
    __syncthreads();
    for (int l = tid; l < 105*32; l += 256){
      int o = l>>5, c = l&31;
      sdw[o*36+c] = dw[o*256 + ch*32 + c];
    }
    __syncthreads();
    float a0[7], a1[7];
    #pragma unroll
    for (int oj=0;oj<7;oj++){ a0[oj]=0.f; a1[oj]=0.f; }
    const float* x0 = &sx[(ppg*2  )*260 + ch*32];
    const float* x1 = &sx[(ppg*2+1)*260 + ch*32];
    #pragma unroll
    for (int c4=0; c4<8; c4++){
      float4 xa = *(const float4*)&x0[c4*4];
      float4 xb = *(const float4*)&x1[c4*4];
      #pragma unroll
      for (int oj=0;oj<7;oj++){
        int o = og*7+oj;
        if (o < 105){
          float4 wv = *(const float4*)&sdw[o*36 + c4*4];
          a0[oj] += xa.x*wv.x + xa.y*wv.y + xa.z*wv.z + xa.w*wv.w;
          a1[oj] += xb.x*wv.x + xb.y*wv.y + xb.z*wv.z + xb.w*wv.w;
        }
      }
    }
    #pragma unroll
    for (int oj=0;oj<7;oj++){
      int o = og*7+oj;
      if (o < 105){
        sy[(ppg*2  )*112+o] += a0[oj];
        sy[(ppg*2+1)*112+o] += a1[oj];
      }
    }
  }
  __syncthreads();
  // softmax over first 41 per patch (32 threads)
  if (tid < 32){
    float* y = &sy[tid*112];
    float m = y[0];
    for (int i=1;i<41;i++) m = fmaxf(m, y[i]);
    float s = 0.f;
    for (int i=0;i<41;i++){ float e = expf(y[i]-m); y[i] = e; s += e; }
    float inv = 1.f/s;
    for (int i=0;i<41;i++) y[i] *= inv;
  }
  __syncthreads();
  // write depth + ctx (coalesced)
  for (int l = tid; l < 32*41; l += 256){
    int pp = l/41, dd = l%41;
    v11_depth[(size_t)(pbase+pp)*41 + dd] = sy[pp*112+dd];
  }
  for (int l = tid; l < 32*64; l += 256){
    int pp = l>>6, c = l&63;
    v11_ctx[(size_t)(pbase+pp)*64 + c] = sy[pp*112 + 41 + c];
  }
}

// voxel rank per frustum point (trunc-toward-zero, rank aliasing allowed)
__global__ __launch_bounds__(256) void rank_v11(){
  int idx = blockIdx.x*256 + threadIdx.x;
  if (idx >= NPTS) return;
  int im = idx / 28864;
  int r  = idx % 28864;
  int d  = r / 704; int pix = r % 704;
  int h = pix / 44, w = pix % 44;
  const double* g = v11_geom + im*24;
  double fx = (double)w * (703.0/43.0);
  double fy = (double)h * 17.0;
  double fz = 4.0 + (double)d;
  double px = fx - g[18], py = fy - g[19], pz = fz - g[20];
  double q0 = g[0]*px + g[1]*py + g[2]*pz;
  double q1 = g[3]*px + g[4]*py + g[5]*pz;
  double q2 = g[6]*px + g[7]*py + g[8]*pz;
  q0 *= q2; q1 *= q2;
  double o0 = g[9]*q0  + g[10]*q1 + g[11]*q2 + g[21];
  double o1 = g[12]*q0 + g[13]*q1 + g[14]*q2 + g[22];
  double o2 = g[15]*q0 + g[16]*q1 + g[17]*q2 + g[23];
  int cx = (int)((o0 + 51.2)/0.8);
  int cy = (int)((o1 + 51.2)/0.8);
  int cz = (int)((o2 + 10.0)/20.0);
  int rank = cx + cy*128 + cz*16384;
  v11_ranks[idx] = (rank >= 0 && rank < 16384) ? rank : -1;
}

// scatter: one lane per (point, channel)
__global__ __launch_bounds__(256) void scatter_v11(){
  long long gid = (long long)blockIdx.x*256 + threadIdx.x;
  int idx = (int)(gid >> 6);
  int c   = (int)(gid & 63);
  if (idx >= NPTS) return;
  int rank = v11_ranks[idx];
  if (rank < 0) return;
  int im = idx / 28864;
  int r  = idx % 28864;
  int d  = r / 704; int pix = r % 704;
  int p = im*704 + pix;
  float val = v11_ctx[(size_t)p*64 + c] * v11_depth[(size_t)p*41 + d];
  atomicAdd(v11_bev + (size_t)rank*64 + c, val);
}

// bev output: [yx][c] -> out1[c][y][x] fp32
__global__ void bevout_v11(float* out1){
  int gid = blockIdx.x*256 + threadIdx.x;
  int c  = gid >> 14;
  int yx = gid & 16383;
  out1[gid] = v11_bev[(size_t)yx*64 + c];
}

// fold enc_w concat([bev,bev]) halves
__global__ void w2_v11(const float* enc_w){
  int gid = blockIdx.x*256 + threadIdx.x;
  if (gid >= 36864) return;
  int o = gid / 576; int rem = gid % 576;
  int ic = rem / 9, t = rem % 9;
  v11_w2[gid] = enc_w[o*1152 + ic*9 + t] + enc_w[o*1152 + (ic+64)*9 + t];
}

// conv2 3x3 SAME + BN2 + ReLU + 7x64 head, fused
__global__ __launch_bounds__(256) void conv2_v11(
    const float* eb, const float* g2, const float* b2_, const float* m2, const float* v2,
    const float* hw, const float* hb, float* out0){
  __shared__ float itile[64*100];     // 25,600 B
  __shared__ float wtile[64*72];      // 18,432 B
  __shared__ float hred[4*64*7];      //  7,168 B
  int tid = threadIdx.x;
  int og  = tid >> 6;
  int pix = tid & 63;
  int py = pix >> 3, px = pix & 7;
  int by = blockIdx.y, bx = blockIdx.x;
  for (int l = tid; l < 6400; l += 256){
    int ic = l / 100, rem = l % 100;
    int iy = rem / 10, ix = rem % 10;
    int gy = by*8 + iy - 1, gx = bx*8 + ix - 1;
    itile[l] = (gy>=0 && gy<128 && gx>=0 && gx<128) ? v11_bev[(size_t)(gy*128+gx)*64 + ic] : 0.f;
  }
  float acc[16];
  #pragma unroll
  for (int j=0;j<16;j++) acc[j]=0.f;
  for (int it=0; it<64; it+=8){
    __syncthreads();
    for (int l = tid; l < 64*72; l += 256){
      int oc = l / 72, rem = l % 72;
      wtile[l] = v11_w2[oc*576 + it*9 + rem];
    }
    __syncthreads();
    for (int icl=0; icl<8; icl++){
      int ic = it + icl;
      const float* ibase = itile + ic*100 + py*10 + px;
      float iv[9];
      #pragma unroll
      for (int t=0;t<9;t++) iv[t] = ibase[(t/3)*10 + (t%3)];
      const float* wbase = wtile + (og*16)*72 + icl*9;
      #pragma unroll
      for (int j=0;j<16;j++){
        #pragma unroll
        for (int t=0;t<9;t++) acc[j] += iv[t]*wbase[j*72+t];
      }
    }
  }
  float part[7];
  #pragma unroll
  for (int o=0;o<7;o++) part[o]=0.f;
  for (int j=0;j<16;j++){
    int oc = og*16+j;
    float scale = g2[oc]/sqrtf(v2[oc]+1e-5f);
    float shift = b2_[oc] - m2[oc]*scale;
    float v = (acc[j] + eb[oc])*scale + shift;
    v = v > 0.f ? v : 0.f;
    #pragma unroll
    for (int o=0;o<7;o++) part[o] += hw[o*64+oc]*v;
  }
  __syncthreads();
  for (int o=0;o<7;o++) hred[(og*64+pix)*7+o] = part[o];
  __syncthreads();
  if (og == 0){
    int gy = by*8+py, gx = bx*8+px;
    for (int o=0;o<7;o++){
      float s = hred[pix*7+o] + hred[(64+pix)*7+o] + hred[(128+pix)*7+o]
              + hred[(192+pix)*7+o] + hb[o];
      out0[o*16384 + gy*128 + gx] = s;
    }
  }
}

extern "C" void kernel_launch(void* const* d_in, const int* in_sizes, int n_in,
                              void* d_out, int out_size, void* d_ws, size_t ws_size,
                              hipStream_t stream){
  const float* imgs       = (const float*)d_in[0];
  const float* rots       = (const float*)d_in[1];
  const float* trans      = (const float*)d_in[2];
  const float* intrins    = (const float*)d_in[3];
  const float* post_rots  = (const float*)d_in[4];
  const float* post_trans = (const float*)d_in[5];
  const float* conv_w     = (const float*)d_in[6];
  const float* conv_b     = (const float*)d_in[7];
  const float* bn1_g      = (const float*)d_in[8];
  const float* bn1_b      = (const float*)d_in[9];
  const float* bn1_m      = (const float*)d_in[10];
  const float* bn1_v      = (const float*)d_in[11];
  const float* depth_w    = (const float*)d_in[12];
  const float* depth_b    = (const float*)d_in[13];
  const float* enc_w      = (const float*)d_in[14];
  const float* enc_b      = (const float*)d_in[15];
  const float* bn2_g      = (const float*)d_in[16];
  const float* bn2_b      = (const float*)d_in[17];
  const float* bn2_m      = (const float*)d_in[18];
  const float* bn2_v      = (const float*)d_in[19];
  const float* head_w     = (const float*)d_in[20];
  const float* head_b     = (const float*)d_in[21];

  float* out0 = (float*)d_out;          // (1,7,128,128)
  float* out1 = out0 + 114688;          // (1,64,128,128)

  zero_v11<<<4096, 256, 0, stream>>>();
  geom_v11<<<1, 32, 0, stream>>>(rots, trans, intrins, post_rots, post_trans);
  wt_v11<<<768, 256, 0, stream>>>(conv_w);
  conv1_v11<<<NPATCH/32, 256, 0, stream>>>(imgs, conv_b, bn1_g, bn1_b, bn1_m, bn1_v);
  depth_v11<<<NPATCH/32, 256, 0, stream>>>(depth_w, depth_b);
  rank_v11<<<NPTS/256, 256, 0, stream>>>();
  scatter_v11<<<(NPTS*64)/256, 256, 0, stream>>>();
  w2_v11<<<144, 256, 0, stream>>>(enc_w);
  bevout_v11<<<4096, 256, 0, stream>>>(out1);
  conv2_v11<<<dim3(16,16), 256, 0, stream>>>(enc_b, bn2_g, bn2_b, bn2_m, bn2_v,
                                             head_w, head_b, out0);
}